// Round 1
// baseline (489.228 us; speedup 1.0000x reference)
//
#include <hip/hip_runtime.h>

#define BB 16
#define LL 8192
#define C_IN 512
#define C_OUT 512
#define NWIN 8189
#define NROWS (BB * LL)          // 131072 y-rows
#define NOUT_ROWS (BB * NWIN)    // 131024 output rows

// Kernel 1: per (b,l) row, compute y1 = x·W_in[1,:] + b_in[1], y2 = x·W_in[2,:] + b_in[2].
// One wave (64 lanes) per row; lane handles 2 float4 chunks (512 floats / row).
__global__ __launch_bounds__(256) void qconv_y_kernel(
    const float* __restrict__ x,
    const float* __restrict__ W_in,
    const float* __restrict__ b_in,
    float2* __restrict__ y) {
    int row  = blockIdx.x * 4 + (threadIdx.x >> 6);
    int lane = threadIdx.x & 63;
    if (row >= NROWS) return;

    const float4* xr = (const float4*)(x + (size_t)row * C_IN);
    const float4* w1 = (const float4*)(W_in + C_IN);       // row q=1
    const float4* w2 = (const float4*)(W_in + 2 * C_IN);   // row q=2

    float s1 = 0.f, s2 = 0.f;
#pragma unroll
    for (int j = 0; j < 2; ++j) {
        int idx = lane + j * 64;        // C_IN/4 = 128 float4 per row
        float4 xv = xr[idx];
        float4 a  = w1[idx];
        float4 b  = w2[idx];
        s1 += xv.x * a.x + xv.y * a.y + xv.z * a.z + xv.w * a.w;
        s2 += xv.x * b.x + xv.y * b.y + xv.z * b.z + xv.w * b.w;
    }
#pragma unroll
    for (int off = 32; off; off >>= 1) {
        s1 += __shfl_down(s1, off, 64);
        s2 += __shfl_down(s2, off, 64);
    }
    if (lane == 0) y[row] = make_float2(s1 + b_in[1], s2 + b_in[2]);
}

// Kernel 2: per output row (b,w): q[k] = cos(y1[w+k]+vw1)*cos(y2[w+k]+vw2), k=0..2
// then out[b,w,co] = sum_k q[k]*W_out[co,k] + b_out[co].
// 256-thread block handles 2 rows; each thread writes one float4 (4 channels).
__global__ __launch_bounds__(256) void qconv_out_kernel(
    const float2* __restrict__ y,
    const float* __restrict__ vqc_w,
    const float* __restrict__ W_out,
    const float* __restrict__ b_out,
    float* __restrict__ out) {
    int row = blockIdx.x * 2 + (threadIdx.x >> 7);
    if (row >= NOUT_ROWS) return;
    int t = threadIdx.x & 127;

    int b = row / NWIN;               // row = b*NWIN + w
    int w = row - b * NWIN;

    const float2* yr = y + (size_t)b * LL + w;
    float vw1 = vqc_w[(size_t)row * 3 + 1];
    float vw2 = vqc_w[(size_t)row * 3 + 2];

    float q0, q1, q2;
    {
        float2 y0 = yr[0], y1v = yr[1], y2v = yr[2];
        q0 = cosf(y0.x + vw1)  * cosf(y0.y + vw2);
        q1 = cosf(y1v.x + vw1) * cosf(y1v.y + vw2);
        q2 = cosf(y2v.x + vw1) * cosf(y2v.y + vw2);
    }

    int co = t * 4;
    const float* wo = W_out + (size_t)co * 3;   // W_out is (C_OUT, 3) row-major
    float4 r;
    r.x = q0 * wo[0] + q1 * wo[1]  + q2 * wo[2]  + b_out[co + 0];
    r.y = q0 * wo[3] + q1 * wo[4]  + q2 * wo[5]  + b_out[co + 1];
    r.z = q0 * wo[6] + q1 * wo[7]  + q2 * wo[8]  + b_out[co + 2];
    r.w = q0 * wo[9] + q1 * wo[10] + q2 * wo[11] + b_out[co + 3];

    ((float4*)(out + (size_t)row * C_OUT))[t] = r;
}

extern "C" void kernel_launch(void* const* d_in, const int* in_sizes, int n_in,
                              void* d_out, int out_size, void* d_ws, size_t ws_size,
                              hipStream_t stream) {
    const float* x     = (const float*)d_in[0];   // (16, 8192, 512)
    const float* W_in  = (const float*)d_in[1];   // (3, 512)
    const float* b_in  = (const float*)d_in[2];   // (3,)
    const float* W_out = (const float*)d_in[3];   // (512, 3)
    const float* b_out = (const float*)d_in[4];   // (512,)
    const float* vqc_w = (const float*)d_in[5];   // (16, 8189, 1, 3)
    float* out = (float*)d_out;                   // (16, 8189, 512) f32

    float2* y = (float2*)d_ws;                    // B*L float2 = 1 MB scratch

    // Kernel 1: 131072 rows, 4 rows per 256-thread block.
    qconv_y_kernel<<<NROWS / 4, 256, 0, stream>>>(x, W_in, b_in, y);

    // Kernel 2: 131024 output rows, 2 rows per 256-thread block.
    qconv_out_kernel<<<(NOUT_ROWS + 1) / 2, 256, 0, stream>>>(y, vqc_w, W_out, b_out, out);
}

// Round 3
// 480.024 us; speedup vs baseline: 1.0192x; 1.0192x over previous
//
#include <hip/hip_runtime.h>

#define BB 16
#define LL 8192
#define C_IN 512
#define C_OUT 512
#define NWIN 8189
#define NROWS (BB * LL)          // 131072 y-rows
#define NOUT_ROWS (BB * NWIN)    // 131024 output rows

// Kernel 1: per (b,l) row, compute y1 = x·W_in[1,:] + b_in[1], y2 = x·W_in[2,:] + b_in[2].
// One wave (64 lanes) per row; lane handles 2 float4 chunks (512 floats / row).
// Memory-bound: streams 268 MB of x, fully coalesced.
__global__ __launch_bounds__(256) void qconv_y_kernel(
    const float* __restrict__ x,
    const float* __restrict__ W_in,
    const float* __restrict__ b_in,
    float2* __restrict__ y) {
    int row  = blockIdx.x * 4 + (threadIdx.x >> 6);
    int lane = threadIdx.x & 63;
    if (row >= NROWS) return;

    const float4* xr = (const float4*)(x + (size_t)row * C_IN);
    const float4* w1 = (const float4*)(W_in + C_IN);       // row q=1
    const float4* w2 = (const float4*)(W_in + 2 * C_IN);   // row q=2

    float s1 = 0.f, s2 = 0.f;
#pragma unroll
    for (int j = 0; j < 2; ++j) {
        int idx = lane + j * 64;        // C_IN/4 = 128 float4 per row
        float4 xv = xr[idx];
        float4 a  = w1[idx];
        float4 b  = w2[idx];
        s1 += xv.x * a.x + xv.y * a.y + xv.z * a.z + xv.w * a.w;
        s2 += xv.x * b.x + xv.y * b.y + xv.z * b.z + xv.w * b.w;
    }
#pragma unroll
    for (int off = 32; off; off >>= 1) {
        s1 += __shfl_down(s1, off, 64);
        s2 += __shfl_down(s2, off, 64);
    }
    if (lane == 0) y[row] = make_float2(s1 + b_in[1], s2 + b_in[2]);
}

// Kernel 2: per output row (b,w): q[k] = cos(y1[w+k]+vw1)*cos(y2[w+k]+vw2), k=0..2
// computed ONCE per row (3 threads, LDS broadcast), then
// out[b,w,co] = sum_k q[k]*W_out[co,k] + b_out[co] — write-bound, float4 stores.
// 256-thread block handles 2 rows; each thread writes one float4 (4 channels).
__global__ __launch_bounds__(256) void qconv_out_kernel(
    const float2* __restrict__ y,
    const float* __restrict__ vqc_w,
    const float* __restrict__ W_out,
    const float* __restrict__ b_out,
    float* __restrict__ out) {
    __shared__ float qs[2][4];
    int half = threadIdx.x >> 7;                 // 0 or 1: which row in block
    int row  = blockIdx.x * 2 + half;            // grid covers exactly NOUT_ROWS
    int t    = threadIdx.x & 127;

    int b = row / NWIN;                          // row = b*NWIN + w
    int w = row - b * NWIN;

    if (t < 3) {
        // q_k for this row; only 3 threads do trig (2 cosf each)
        float vw1 = vqc_w[(size_t)row * 3 + 1];
        float vw2 = vqc_w[(size_t)row * 3 + 2];
        float2 yv = y[(size_t)b * LL + w + t];
        qs[half][t] = cosf(yv.x + vw1) * cosf(yv.y + vw2);
    }
    __syncthreads();

    float q0 = qs[half][0], q1 = qs[half][1], q2 = qs[half][2];

    // W_out is (C_OUT, 3) row-major; channels co..co+3 = 12 floats at 48B-aligned offset
    const float4* wo4 = (const float4*)(W_out + (size_t)t * 12);
    float4 wa = wo4[0];   // W[co][0..2], W[co+1][0]
    float4 wb = wo4[1];   // W[co+1][1..2], W[co+2][0..1]
    float4 wc = wo4[2];   // W[co+2][2], W[co+3][0..2]
    float4 bv = ((const float4*)b_out)[t];

    float4 r;
    r.x = q0 * wa.x + q1 * wa.y + q2 * wa.z + bv.x;
    r.y = q0 * wa.w + q1 * wb.x + q2 * wb.y + bv.y;
    r.z = q0 * wb.z + q1 * wb.w + q2 * wc.x + bv.z;
    r.w = q0 * wc.y + q1 * wc.z + q2 * wc.w + bv.w;

    ((float4*)(out + (size_t)row * C_OUT))[t] = r;
}

extern "C" void kernel_launch(void* const* d_in, const int* in_sizes, int n_in,
                              void* d_out, int out_size, void* d_ws, size_t ws_size,
                              hipStream_t stream) {
    const float* x     = (const float*)d_in[0];   // (16, 8192, 512)
    const float* W_in  = (const float*)d_in[1];   // (3, 512)
    const float* b_in  = (const float*)d_in[2];   // (3,)
    const float* W_out = (const float*)d_in[3];   // (512, 3)
    const float* b_out = (const float*)d_in[4];   // (512,)
    const float* vqc_w = (const float*)d_in[5];   // (16, 8189, 1, 3)
    float* out = (float*)d_out;                   // (16, 8189, 512) f32

    float2* y = (float2*)d_ws;                    // B*L float2 = 1 MB scratch

    // Kernel 1: 131072 rows, 4 rows per 256-thread block.
    qconv_y_kernel<<<NROWS / 4, 256, 0, stream>>>(x, W_in, b_in, y);

    // Kernel 2: 131024 output rows, 2 rows per 256-thread block (exact).
    qconv_out_kernel<<<NOUT_ROWS / 2, 256, 0, stream>>>(y, vqc_w, W_out, b_out, out);
}